// Round 2
// baseline (2460.601 us; speedup 1.0000x reference)
//
#include <hip/hip_runtime.h>
#include <hip/hip_bf16.h>
#include <math.h>

// Problem constants (B,G,N,D,H,DH fixed by the reference)
#define Bn  4
#define Gn  2
#define Nn  2048
#define Dn  512
#define Hn  8
#define DHn 64
#define DIn 512
#define N1n 2049   // N + 1 null position

// Workspace layout (float offsets).  Q is reused as O (attention output,
// head-major) — each attn thread overwrites only its own Q row after loading
// it into registers, so no cross-thread hazard.
#define QOFF 0
#define KOFF (Bn*Gn*Hn*Nn*DHn)                       // 8,388,608
#define VOFF (KOFF + Bn*Gn*Hn*N1n*DHn)               // +8,392,704
// total floats = VOFF + Bn*Gn*Hn*N1n*DHn = 25,174,016 (~96.0 MiB)

// ---------------------------------------------------------------------------
// Kernel 1: grouped QKV projection.  C[m,e] = sum_d x_row(m)[d] * W[e][d]
// 64x64 tile, 256 threads, 4x4 micro-tile, fp32.  Epilogue scatters into
// head-major Q/K/V layouts; K/V go to position n+1 (slot 0 = null kv).
// ---------------------------------------------------------------------------
__global__ __launch_bounds__(256) void qkv_proj(const float* __restrict__ x,
                                                const float* __restrict__ Wq,
                                                const float* __restrict__ Wkv,
                                                float* __restrict__ ws)
{
    const int g  = blockIdx.z;
    const int m0 = blockIdx.x * 64;     // row tile over b*N
    const int e0 = blockIdx.y * 64;     // col tile over 1536 (q|k|v)
    const int tid = threadIdx.x;
    const int tx = tid & 15, ty = tid >> 4;

    __shared__ float As[32 * 68];       // As[kk][r] = A[m0+r][k0+kk]
    __shared__ float Bs[32 * 68];       // Bs[kk][c] = W[e0+c][k0+kk]

    const float* wbase = (e0 < 512)
        ? (Wq  + (size_t)g * 512  * 512 + (size_t)e0 * 512)
        : (Wkv + (size_t)g * 1024 * 512 + (size_t)(e0 - 512) * 512);

    float acc[4][4] = {{0.f}};

    for (int k0 = 0; k0 < 512; k0 += 32) {
        #pragma unroll
        for (int i = 0; i < 2; ++i) {
            const int f  = tid + i * 256;       // [0,512) float4 slots
            const int r  = f >> 3;              // tile row 0..63
            const int kc = (f & 7) * 4;         // k offset 0..28
            const int m  = m0 + r;
            const float* ap = x + ((size_t)((m >> 11) * Gn + g) * Nn + (m & 2047)) * Dn + k0 + kc;
            float4 av = *(const float4*)ap;
            As[(kc+0)*68 + r] = av.x;
            As[(kc+1)*68 + r] = av.y;
            As[(kc+2)*68 + r] = av.z;
            As[(kc+3)*68 + r] = av.w;
            const float* wp = wbase + (size_t)r * 512 + k0 + kc;
            float4 wv = *(const float4*)wp;
            Bs[(kc+0)*68 + r] = wv.x;
            Bs[(kc+1)*68 + r] = wv.y;
            Bs[(kc+2)*68 + r] = wv.z;
            Bs[(kc+3)*68 + r] = wv.w;
        }
        __syncthreads();
        #pragma unroll
        for (int kk = 0; kk < 32; ++kk) {
            float4 a = *(const float4*)&As[kk*68 + ty*4];
            float4 b = *(const float4*)&Bs[kk*68 + tx*4];
            float av[4] = {a.x, a.y, a.z, a.w};
            float bv[4] = {b.x, b.y, b.z, b.w};
            #pragma unroll
            for (int i = 0; i < 4; ++i)
                #pragma unroll
                for (int j = 0; j < 4; ++j)
                    acc[i][j] += av[i] * bv[j];
        }
        __syncthreads();
    }

    // Epilogue: e0 is 64-aligned -> whole tile is one section & one head.
    const int sec = e0 >> 9;              // 0=q 1=k 2=v
    const int h   = (e0 & 511) >> 6;
    float* Q = ws + QOFF;
    float* K = ws + KOFF;
    float* V = ws + VOFF;

    #pragma unroll
    for (int i = 0; i < 4; ++i) {
        const int m = m0 + ty*4 + i;
        const int b = m >> 11, n = m & 2047;
        const int bgh = (b * Gn + g) * Hn + h;
        float4 val = make_float4(acc[i][0], acc[i][1], acc[i][2], acc[i][3]);
        if (sec == 0)
            *(float4*)(Q + ((size_t)bgh * Nn  + n    ) * 64 + tx*4) = val;
        else if (sec == 1)
            *(float4*)(K + ((size_t)bgh * N1n + n + 1) * 64 + tx*4) = val;
        else
            *(float4*)(V + ((size_t)bgh * N1n + n + 1) * 64 + tx*4) = val;
    }
}

// ---------------------------------------------------------------------------
// Kernel 2: RoPE on Q and K (in place), plus null-kv fill at K/V position 0.
// pair p (<32): lo' = lo*cos(a[p]) - hi*sin(a[p]); hi' = hi*cos(a[p+32]) + lo*sin(a[p+32])
// ---------------------------------------------------------------------------
__global__ __launch_bounds__(256) void rope_null(float* __restrict__ ws,
                                                 const float* __restrict__ rot_q,
                                                 const float* __restrict__ rot_k,
                                                 const float* __restrict__ nkv)
{
    const long long idx = (long long)blockIdx.x * 256 + threadIdx.x;
    const long long QP = (long long)Bn * Gn * Hn * Nn * 32;   // 4,194,304
    float* Q = ws + QOFF;
    float* K = ws + KOFF;
    float* V = ws + VOFF;

    if (idx < QP) {
        const int p = (int)(idx & 31);
        const long long row = idx >> 5;          // bgh*N + n
        const int n = (int)(row & 2047);
        const float a1 = rot_q[n*64 + p],      a2 = rot_q[n*64 + p + 32];
        const float c1 = cosf(a1), s1 = sinf(a1);
        const float c2 = cosf(a2), s2 = sinf(a2);
        float* base = Q + row * 64;
        const float lo = base[p], hi = base[p + 32];
        base[p]      = lo * c1 - hi * s1;
        base[p + 32] = hi * c2 + lo * s2;
    } else if (idx < 2 * QP) {
        const long long i2 = idx - QP;
        const int p = (int)(i2 & 31);
        const long long row = i2 >> 5;
        const int n = (int)(row & 2047);
        const long long bgh = row >> 11;
        const float a1 = rot_k[n*64 + p],      a2 = rot_k[n*64 + p + 32];
        const float c1 = cosf(a1), s1 = sinf(a1);
        const float c2 = cosf(a2), s2 = sinf(a2);
        float* base = K + (bgh * N1n + n + 1) * 64;
        const float lo = base[p], hi = base[p + 32];
        base[p]      = lo * c1 - hi * s1;
        base[p + 32] = hi * c2 + lo * s2;
    } else {
        const int i = (int)(idx - 2 * QP);       // [0, 8192)
        if (i < 2 * Bn * Gn * Hn * DHn) {
            const int s   = i >> 12;             // 0=k-null, 1=v-null
            const int rem = i & 4095;
            const int bgh = rem >> 6;            // (b*G+g)*H+h, b in high bits
            const int t   = rem & 63;
            const int gh  = bgh & 15;            // g*H + h (broadcast over b)
            const float val = nkv[s * (Gn*Hn*DHn) + gh * 64 + t];
            float* dst = (s == 0 ? K : V) + (long long)bgh * N1n * 64 + t;
            *dst = val;
        }
    }
}

// ---------------------------------------------------------------------------
// Kernel 3: flash attention, fp32.  One q-row per thread (q[64], o[64] regs).
// K/V staged in LDS 32 keys at a time; online softmax in 8-key subtiles.
// 2049 keys = 64 full tiles of 32 + 1 tail key.
// Output O overwrites the thread's own Q row (head-major layout) — safe
// because each Q row is read only by its owning thread, into registers,
// before any O write happens.
// ---------------------------------------------------------------------------
__global__ __launch_bounds__(256) void attn(float* __restrict__ ws)
{
    const int tid = threadIdx.x;
    const int bid = blockIdx.x;
    const int bgh = bid >> 3;           // (b*G+g)*H + h
    const int qt  = bid & 7;
    const int n   = qt * 256 + tid;

    float* Q = ws + QOFF;
    const float* K = ws + KOFF;
    const float* V = ws + VOFF;

    __shared__ float Ks[32 * 64];
    __shared__ float Vs[32 * 64];

    float q[64], o[64];
    float* qp = Q + ((size_t)bgh * Nn + n) * 64;
    #pragma unroll
    for (int d = 0; d < 64; d += 4) {
        float4 v = *(const float4*)(qp + d);
        q[d]   = v.x * 0.125f; q[d+1] = v.y * 0.125f;
        q[d+2] = v.z * 0.125f; q[d+3] = v.w * 0.125f;
        o[d] = 0.f; o[d+1] = 0.f; o[d+2] = 0.f; o[d+3] = 0.f;
    }
    float mrun = -INFINITY, lrun = 0.f;

    const float* kb = K + (size_t)bgh * N1n * 64;
    const float* vb = V + (size_t)bgh * N1n * 64;

    for (int kt = 0; kt < 2048; kt += 32) {
        #pragma unroll
        for (int i = 0; i < 2; ++i) {
            const int f = tid + i * 256;          // [0,512) float4 slots
            *(float4*)&Ks[f*4] = *(const float4*)(kb + (size_t)kt*64 + f*4);
            *(float4*)&Vs[f*4] = *(const float4*)(vb + (size_t)kt*64 + f*4);
        }
        __syncthreads();

        #pragma unroll 1
        for (int j0 = 0; j0 < 32; j0 += 8) {
            float s[8];
            float tmax = mrun;
            #pragma unroll
            for (int jj = 0; jj < 8; ++jj) {
                float accv = 0.f;
                #pragma unroll
                for (int d = 0; d < 64; d += 4) {
                    float4 kv = *(const float4*)&Ks[(j0+jj)*64 + d];
                    accv += q[d]*kv.x + q[d+1]*kv.y + q[d+2]*kv.z + q[d+3]*kv.w;
                }
                s[jj] = accv;
                tmax = fmaxf(tmax, accv);
            }
            const float corr = __expf(mrun - tmax);
            lrun *= corr;
            #pragma unroll
            for (int d = 0; d < 64; ++d) o[d] *= corr;
            #pragma unroll
            for (int jj = 0; jj < 8; ++jj) {
                const float p = __expf(s[jj] - tmax);
                lrun += p;
                #pragma unroll
                for (int d = 0; d < 64; d += 4) {
                    float4 vv = *(const float4*)&Vs[(j0+jj)*64 + d];
                    o[d]   += p * vv.x; o[d+1] += p * vv.y;
                    o[d+2] += p * vv.z; o[d+3] += p * vv.w;
                }
            }
            mrun = tmax;
        }
        __syncthreads();
    }

    // tail key (index 2048), read directly from global (wave-uniform)
    {
        const float* kp = kb + (size_t)2048 * 64;
        const float* vp = vb + (size_t)2048 * 64;
        float accv = 0.f;
        #pragma unroll
        for (int d = 0; d < 64; ++d) accv += q[d] * kp[d];
        const float tmax = fmaxf(mrun, accv);
        const float corr = __expf(mrun - tmax);
        const float p    = __expf(accv - tmax);
        lrun = lrun * corr + p;
        #pragma unroll
        for (int d = 0; d < 64; ++d) o[d] = o[d] * corr + p * vp[d];
    }

    // write O over own Q row (head-major [bgh, n, d])
    const float inv = 1.f / lrun;
    #pragma unroll
    for (int d = 0; d < 64; d += 4) {
        float4 vv = make_float4(o[d]*inv, o[d+1]*inv, o[d+2]*inv, o[d+3]*inv);
        *(float4*)(qp + d) = vv;
    }
}

// ---------------------------------------------------------------------------
// Kernel 4: output projection.  out[m,dcol] = sum_e O[m,e] * Wout[g][dcol][e]
// O is head-major: O[m, e=h*64+dd] lives at ws[((bg*8+h)*2048+n)*64 + dd].
// 4-float k-chunks never cross a 64 (head) boundary, so float4 loads hold.
// ---------------------------------------------------------------------------
__global__ __launch_bounds__(256) void out_proj(const float* __restrict__ ws,
                                                const float* __restrict__ Wout,
                                                float* __restrict__ out)
{
    const int g  = blockIdx.z;
    const int m0 = blockIdx.x * 64;
    const int c0 = blockIdx.y * 64;     // d-col tile over 512
    const int tid = threadIdx.x;
    const int tx = tid & 15, ty = tid >> 4;

    __shared__ float As[32 * 68];
    __shared__ float Bs[32 * 68];

    const float* O = ws + QOFF;
    const float* wbase = Wout + (size_t)g * 512 * 512 + (size_t)c0 * 512;

    float acc[4][4] = {{0.f}};

    for (int k0 = 0; k0 < 512; k0 += 32) {
        #pragma unroll
        for (int i = 0; i < 2; ++i) {
            const int f  = tid + i * 256;
            const int r  = f >> 3;
            const int kc = (f & 7) * 4;
            const int m  = m0 + r;
            const int b  = m >> 11, n = m & 2047;
            const int e  = k0 + kc;
            const int h  = e >> 6, dd = e & 63;
            const float* ap = O + (((size_t)((b * Gn + g) * Hn + h) * Nn + n) * 64 + dd);
            float4 av = *(const float4*)ap;
            As[(kc+0)*68 + r] = av.x;
            As[(kc+1)*68 + r] = av.y;
            As[(kc+2)*68 + r] = av.z;
            As[(kc+3)*68 + r] = av.w;
            const float* wp = wbase + (size_t)r * 512 + k0 + kc;
            float4 wv = *(const float4*)wp;
            Bs[(kc+0)*68 + r] = wv.x;
            Bs[(kc+1)*68 + r] = wv.y;
            Bs[(kc+2)*68 + r] = wv.z;
            Bs[(kc+3)*68 + r] = wv.w;
        }
        __syncthreads();
        #pragma unroll
        for (int kk = 0; kk < 32; ++kk) {
            float4 a = *(const float4*)&As[kk*68 + ty*4];
            float4 b = *(const float4*)&Bs[kk*68 + tx*4];
            float av[4] = {a.x, a.y, a.z, a.w};
            float bv[4] = {b.x, b.y, b.z, b.w};
            #pragma unroll
            for (int i = 0; i < 4; ++i)
                #pragma unroll
                for (int j = 0; j < 4; ++j)
                    acc[i][j] += av[i] * bv[j];
        }
        __syncthreads();
    }

    #pragma unroll
    for (int i = 0; i < 4; ++i) {
        const int m = m0 + ty*4 + i;
        const int b = m >> 11, n = m & 2047;
        float4 val = make_float4(acc[i][0], acc[i][1], acc[i][2], acc[i][3]);
        *(float4*)(out + ((size_t)(b * Gn + g) * Nn + n) * Dn + c0 + tx*4) = val;
    }
}

// ---------------------------------------------------------------------------
extern "C" void kernel_launch(void* const* d_in, const int* in_sizes, int n_in,
                              void* d_out, int out_size, void* d_ws, size_t ws_size,
                              hipStream_t stream)
{
    const float* x     = (const float*)d_in[0];
    const float* Wq    = (const float*)d_in[1];
    const float* Wkv   = (const float*)d_in[2];
    const float* Wout  = (const float*)d_in[3];
    const float* nkv   = (const float*)d_in[4];
    const float* rot_q = (const float*)d_in[5];
    const float* rot_k = (const float*)d_in[6];
    float* out = (float*)d_out;
    float* ws  = (float*)d_ws;
    // requires ws_size >= 25,174,016 floats (~96.0 MiB)

    qkv_proj<<<dim3(128, 24, 2), 256, 0, stream>>>(x, Wq, Wkv, ws);

    const long long rope_total = 2LL * Bn * Gn * Hn * Nn * 32 + 2LL * Bn * Gn * Hn * DHn;
    rope_null<<<dim3((unsigned)((rope_total + 255) / 256)), 256, 0, stream>>>(ws, rot_q, rot_k, nkv);

    attn<<<dim3(Bn * Gn * Hn * (Nn / 256)), 256, 0, stream>>>(ws);

    out_proj<<<dim3(128, 8, 2), 256, 0, stream>>>(ws, Wout, out);
}

// Round 3
// 707.097 us; speedup vs baseline: 3.4799x; 3.4799x over previous
//
#include <hip/hip_runtime.h>
#include <hip/hip_bf16.h>
#include <math.h>

// Problem constants
#define Bn  4
#define Gn  2
#define Nn  2048
#define Dn  512
#define Hn  8
#define DHn 64
#define N1n 2049
#define NPAD 2112          // keys padded to 33 tiles of 64 (rows >2048 masked)
#define BGH (Bn*Gn*Hn)     // 64

// softmax scale folded with log2(e):  s' = (q.k) * 0.125 * log2e, exp2 domain
#define SCL 0.18033688011112042f

typedef short short8 __attribute__((ext_vector_type(8)));
typedef float float4v __attribute__((ext_vector_type(4)));

// Workspace byte offsets
#define O_B   ((size_t)0)                        // fp32 [64][2048][64]  33,554,432 B
#define QB_B  ((size_t)33554432)                 // bf16 [64][2048][64]  16,777,216 B
#define KB_B  ((size_t)50331648)                 // bf16 [64][2112][64]  17,301,504 B
#define VT_B  ((size_t)67633152)                 // bf16 [64][64][2112]  17,301,504 B
#define CQ_B  ((size_t)84934656)                 // fp32 [2048*64] cos(rot_q)
#define SQ_B  ((size_t)85458944)
#define CK_B  ((size_t)85983232)
#define SK_B  ((size_t)86507520)
// end = 87,031,808 B (~83 MiB)

static __device__ __forceinline__ unsigned short f2bf(float x) {
    union { float f; unsigned int u; } c; c.f = x;
    unsigned int r = c.u + 0x7fffu + ((c.u >> 16) & 1u);   // RNE
    return (unsigned short)(r >> 16);
}

// ---------------------------------------------------------------------------
// Kernel 0: cos/sin tables for rope + null-kv fill (bf16).
// ---------------------------------------------------------------------------
__global__ __launch_bounds__(256) void misc_prep(const float* __restrict__ rot_q,
                                                 const float* __restrict__ rot_k,
                                                 const float* __restrict__ nkv,
                                                 char* __restrict__ wsb)
{
    const int idx = blockIdx.x * 256 + threadIdx.x;
    float* ctq = (float*)(wsb + CQ_B);
    float* stq = (float*)(wsb + SQ_B);
    float* ctk = (float*)(wsb + CK_B);
    float* stk = (float*)(wsb + SK_B);
    unsigned short* Kb = (unsigned short*)(wsb + KB_B);
    unsigned short* Vt = (unsigned short*)(wsb + VT_B);

    if (idx < 131072) {
        float a = rot_q[idx];
        ctq[idx] = cosf(a);  stq[idx] = sinf(a);
    } else if (idx < 262144) {
        int i = idx - 131072;
        float a = rot_k[i];
        ctk[i] = cosf(a);  stk[i] = sinf(a);
    } else if (idx < 262144 + 4096) {
        int i = idx - 262144;                 // null K
        int bgh = i >> 6, dh = i & 63;
        int gh = bgh & 15;
        Kb[(size_t)bgh * NPAD * 64 + dh] = f2bf(nkv[gh * 64 + dh]);
    } else if (idx < 262144 + 8192) {
        int i = idx - 262144 - 4096;          // null V
        int bgh = i >> 6, dh = i & 63;
        int gh = bgh & 15;
        Vt[((size_t)bgh * 64 + dh) * NPAD] = f2bf(nkv[1024 + gh * 64 + dh]);
    }
}

// ---------------------------------------------------------------------------
// Kernel 1: grouped QKV projection (fp32 mainloop, 64x64 tile, 4x4 micro).
// Epilogue: rope (shfl partner) + scale-fold for Q, rope for K, V transposed;
// all written as bf16 into attention-friendly layouts.
// ---------------------------------------------------------------------------
__global__ __launch_bounds__(256) void qkv_proj(const float* __restrict__ x,
                                                const float* __restrict__ Wq,
                                                const float* __restrict__ Wkv,
                                                char* __restrict__ wsb)
{
    const int g  = blockIdx.z;
    const int m0 = blockIdx.x * 64;
    const int e0 = blockIdx.y * 64;
    const int tid = threadIdx.x;
    const int tx = tid & 15, ty = tid >> 4;

    __shared__ float As[32 * 68];
    __shared__ float Bs[32 * 68];

    const float* wbase = (e0 < 512)
        ? (Wq  + (size_t)g * 512  * 512 + (size_t)e0 * 512)
        : (Wkv + (size_t)g * 1024 * 512 + (size_t)(e0 - 512) * 512);

    float acc[4][4] = {{0.f}};

    for (int k0 = 0; k0 < 512; k0 += 32) {
        #pragma unroll
        for (int i = 0; i < 2; ++i) {
            const int f  = tid + i * 256;
            const int r  = f >> 3;
            const int kc = (f & 7) * 4;
            const int m  = m0 + r;
            const float* ap = x + ((size_t)((m >> 11) * Gn + g) * Nn + (m & 2047)) * Dn + k0 + kc;
            float4 av = *(const float4*)ap;
            As[(kc+0)*68 + r] = av.x; As[(kc+1)*68 + r] = av.y;
            As[(kc+2)*68 + r] = av.z; As[(kc+3)*68 + r] = av.w;
            const float* wp = wbase + (size_t)r * 512 + k0 + kc;
            float4 wv = *(const float4*)wp;
            Bs[(kc+0)*68 + r] = wv.x; Bs[(kc+1)*68 + r] = wv.y;
            Bs[(kc+2)*68 + r] = wv.z; Bs[(kc+3)*68 + r] = wv.w;
        }
        __syncthreads();
        #pragma unroll
        for (int kk = 0; kk < 32; ++kk) {
            float4 a = *(const float4*)&As[kk*68 + ty*4];
            float4 b = *(const float4*)&Bs[kk*68 + tx*4];
            float av[4] = {a.x, a.y, a.z, a.w};
            float bv[4] = {b.x, b.y, b.z, b.w};
            #pragma unroll
            for (int i = 0; i < 4; ++i)
                #pragma unroll
                for (int j = 0; j < 4; ++j)
                    acc[i][j] += av[i] * bv[j];
        }
        __syncthreads();
    }

    const int sec = e0 >> 9;              // 0=q 1=k 2=v (block-uniform)
    const int h   = (e0 & 511) >> 6;
    unsigned short* Qb = (unsigned short*)(wsb + QB_B);
    unsigned short* Kb = (unsigned short*)(wsb + KB_B);
    unsigned short* Vt = (unsigned short*)(wsb + VT_B);

    if (sec == 0) {
        const float* ct = (const float*)(wsb + CQ_B);
        const float* st = (const float*)(wsb + SQ_B);
        #pragma unroll
        for (int i = 0; i < 4; ++i) {
            const int m = m0 + ty*4 + i;
            const int b = m >> 11, n = m & 2047;
            const int bgh = (b * Gn + g) * Hn + h;
            float4 cv = *(const float4*)(ct + n*64 + tx*4);
            float4 sv = *(const float4*)(st + n*64 + tx*4);
            float o[4];
            #pragma unroll
            for (int j = 0; j < 4; ++j) {
                float prt = __shfl_xor(acc[i][j], 8);     // partner col +-32
                float rh  = (tx < 8) ? -prt : prt;
                o[j] = (acc[i][j] * (&cv.x)[j] + rh * (&sv.x)[j]) * SCL;
            }
            ushort4 w = { f2bf(o[0]), f2bf(o[1]), f2bf(o[2]), f2bf(o[3]) };
            *(ushort4*)(Qb + ((size_t)bgh * Nn + n) * 64 + tx*4) = w;
        }
    } else if (sec == 1) {
        const float* ct = (const float*)(wsb + CK_B);
        const float* st = (const float*)(wsb + SK_B);
        #pragma unroll
        for (int i = 0; i < 4; ++i) {
            const int m = m0 + ty*4 + i;
            const int b = m >> 11, n = m & 2047;
            const int bgh = (b * Gn + g) * Hn + h;
            float4 cv = *(const float4*)(ct + n*64 + tx*4);
            float4 sv = *(const float4*)(st + n*64 + tx*4);
            float o[4];
            #pragma unroll
            for (int j = 0; j < 4; ++j) {
                float prt = __shfl_xor(acc[i][j], 8);
                float rh  = (tx < 8) ? -prt : prt;
                o[j] = acc[i][j] * (&cv.x)[j] + rh * (&sv.x)[j];
            }
            ushort4 w = { f2bf(o[0]), f2bf(o[1]), f2bf(o[2]), f2bf(o[3]) };
            *(ushort4*)(Kb + ((size_t)bgh * NPAD + n + 1) * 64 + tx*4) = w;
        }
    } else {
        #pragma unroll
        for (int i = 0; i < 4; ++i) {
            const int m = m0 + ty*4 + i;
            const int b = m >> 11, n = m & 2047;
            const int bgh = (b * Gn + g) * Hn + h;
            #pragma unroll
            for (int j = 0; j < 4; ++j)
                Vt[((size_t)bgh * 64 + tx*4 + j) * NPAD + n + 1] = f2bf(acc[i][j]);
        }
    }
}

// ---------------------------------------------------------------------------
// Kernel 2: bf16 MFMA flash attention.  Block = 4 waves, 64 q-rows; 64-key
// tiles.  S^T = K.Q^T (D: col=q=lane&15, row=key=quad*4+reg); P relayout via
// per-wave LDS scratch into A-layout; PV accumulates O (D: col=dh, row=q).
// ---------------------------------------------------------------------------
__global__ __launch_bounds__(256, 4) void attn(const unsigned short* __restrict__ Qb,
                                               const unsigned short* __restrict__ Kb,
                                               const unsigned short* __restrict__ Vt,
                                               float* __restrict__ O)
{
    __shared__ alignas(16) unsigned short Ks[64 * 72];
    __shared__ alignas(16) unsigned short Vs[64 * 72];
    __shared__ alignas(16) unsigned short Ps[4 * 16 * 72];

    const int tid  = threadIdx.x;
    const int bid  = blockIdx.x;
    const int bgh  = bid >> 5;           // 32 consecutive blocks share a head -> L2 locality
    const int q0   = (bid & 31) * 64;
    const int wv   = tid >> 6;
    const int ln   = tid & 63;
    const int l15  = ln & 15;
    const int quad = ln >> 4;

    // Q fragment (B-operand): lane holds Q[q=l15][dh = quad*8 + j]
    const int q = q0 + wv * 16 + l15;
    const unsigned short* qrow = Qb + ((size_t)bgh * Nn + q) * 64;
    short8 bq0 = *(const short8*)(qrow + quad * 8);
    short8 bq1 = *(const short8*)(qrow + 32 + quad * 8);

    float4v Oa[4];
    #pragma unroll
    for (int nt = 0; nt < 4; ++nt) Oa[nt] = (float4v){0.f, 0.f, 0.f, 0.f};
    float mrun = -INFINITY, lrun = 0.f;

    const unsigned short* kbase = Kb + (size_t)bgh * NPAD * 64;
    const unsigned short* vbase = Vt + (size_t)bgh * 64 * NPAD;
    unsigned short* Pw = Ps + wv * 16 * 72;

    for (int kt = 0; kt <= 2048; kt += 64) {
        // stage K[kt..kt+63][0..63] and V^T[0..63][kt..kt+63] (bf16)
        #pragma unroll
        for (int c = 0; c < 2; ++c) {
            const int chunk = tid + c * 256;        // 0..511, 8 bf16 each
            const int row = chunk >> 3, c8 = chunk & 7;
            *(float4*)&Ks[row * 72 + c8 * 8] =
                *(const float4*)(kbase + (size_t)(kt + row) * 64 + c8 * 8);
            *(float4*)&Vs[row * 72 + c8 * 8] =
                *(const float4*)(vbase + (size_t)row * NPAD + kt + c8 * 8);
        }
        __syncthreads();

        // S^T tiles: stv[mt][r] = S[q=l15][key = kt + mt*16 + quad*4 + r]
        float4v stv[4];
        #pragma unroll
        for (int mt = 0; mt < 4; ++mt) {
            const unsigned short* krow = &Ks[(mt * 16 + l15) * 72];
            short8 a0 = *(const short8*)(krow + quad * 8);
            short8 a1 = *(const short8*)(krow + 32 + quad * 8);
            float4v z = {0.f, 0.f, 0.f, 0.f};
            z = __builtin_amdgcn_mfma_f32_16x16x32_bf16(a0, bq0, z, 0, 0, 0);
            z = __builtin_amdgcn_mfma_f32_16x16x32_bf16(a1, bq1, z, 0, 0, 0);
            stv[mt] = z;
        }
        if (kt == 2048) {                       // mask pad keys (> 2048)
            #pragma unroll
            for (int mt = 0; mt < 4; ++mt)
                #pragma unroll
                for (int r = 0; r < 4; ++r)
                    if (kt + mt * 16 + quad * 4 + r > 2048) stv[mt][r] = -INFINITY;
        }

        // online softmax over this tile (per q = l15, replicated over quads)
        float tmax = -INFINITY;
        #pragma unroll
        for (int mt = 0; mt < 4; ++mt)
            #pragma unroll
            for (int r = 0; r < 4; ++r) tmax = fmaxf(tmax, stv[mt][r]);
        tmax = fmaxf(tmax, __shfl_xor(tmax, 16));
        tmax = fmaxf(tmax, __shfl_xor(tmax, 32));
        const float newm = fmaxf(mrun, tmax);
        const float corr = __builtin_amdgcn_exp2f(mrun - newm);

        float psum = 0.f;
        #pragma unroll
        for (int mt = 0; mt < 4; ++mt) {
            float pv[4];
            #pragma unroll
            for (int r = 0; r < 4; ++r) {
                pv[r] = __builtin_amdgcn_exp2f(stv[mt][r] - newm);
                psum += pv[r];
            }
            ushort4 w = { f2bf(pv[0]), f2bf(pv[1]), f2bf(pv[2]), f2bf(pv[3]) };
            *(ushort4*)&Pw[l15 * 72 + mt * 16 + quad * 4] = w;
        }
        psum += __shfl_xor(psum, 16);
        psum += __shfl_xor(psum, 32);
        lrun = lrun * corr + psum;
        mrun = newm;

        // rescale O: row r of D is q-row quad*4+r -> pull corr from lane quad*4+r
        const float c0 = __shfl(corr, quad * 4 + 0);
        const float c1 = __shfl(corr, quad * 4 + 1);
        const float c2 = __shfl(corr, quad * 4 + 2);
        const float c3 = __shfl(corr, quad * 4 + 3);
        #pragma unroll
        for (int nt = 0; nt < 4; ++nt) {
            Oa[nt][0] *= c0; Oa[nt][1] *= c1; Oa[nt][2] *= c2; Oa[nt][3] *= c3;
        }

        // PV: A = P (m=q, k=key), B = V^T rows (k=key, n=dh)
        short8 ap0 = *(const short8*)&Pw[l15 * 72 + quad * 8];
        short8 ap1 = *(const short8*)&Pw[l15 * 72 + 32 + quad * 8];
        #pragma unroll
        for (int nt = 0; nt < 4; ++nt) {
            const unsigned short* vrow = &Vs[(nt * 16 + l15) * 72];
            short8 b0 = *(const short8*)(vrow + quad * 8);
            short8 b1 = *(const short8*)(vrow + 32 + quad * 8);
            Oa[nt] = __builtin_amdgcn_mfma_f32_16x16x32_bf16(ap0, b0, Oa[nt], 0, 0, 0);
            Oa[nt] = __builtin_amdgcn_mfma_f32_16x16x32_bf16(ap1, b1, Oa[nt], 0, 0, 0);
        }
        __syncthreads();
    }

    const float inv = 1.f / lrun;
    const float i0 = __shfl(inv, quad * 4 + 0);
    const float i1 = __shfl(inv, quad * 4 + 1);
    const float i2 = __shfl(inv, quad * 4 + 2);
    const float i3 = __shfl(inv, quad * 4 + 3);
    float* obase = O + ((size_t)bgh * Nn + q0 + wv * 16) * 64;
    #pragma unroll
    for (int nt = 0; nt < 4; ++nt) {
        obase[(quad * 4 + 0) * 64 + nt * 16 + l15] = Oa[nt][0] * i0;
        obase[(quad * 4 + 1) * 64 + nt * 16 + l15] = Oa[nt][1] * i1;
        obase[(quad * 4 + 2) * 64 + nt * 16 + l15] = Oa[nt][2] * i2;
        obase[(quad * 4 + 3) * 64 + nt * 16 + l15] = Oa[nt][3] * i3;
    }
}

// ---------------------------------------------------------------------------
// Kernel 3: output projection (fp32).  O is head-major [bgh][n][64].
// ---------------------------------------------------------------------------
__global__ __launch_bounds__(256) void out_proj(const float* __restrict__ O,
                                                const float* __restrict__ Wout,
                                                float* __restrict__ out)
{
    const int g  = blockIdx.z;
    const int m0 = blockIdx.x * 64;
    const int c0 = blockIdx.y * 64;
    const int tid = threadIdx.x;
    const int tx = tid & 15, ty = tid >> 4;

    __shared__ float As[32 * 68];
    __shared__ float Bs[32 * 68];

    const float* wbase = Wout + (size_t)g * 512 * 512 + (size_t)c0 * 512;

    float acc[4][4] = {{0.f}};

    for (int k0 = 0; k0 < 512; k0 += 32) {
        #pragma unroll
        for (int i = 0; i < 2; ++i) {
            const int f  = tid + i * 256;
            const int r  = f >> 3;
            const int kc = (f & 7) * 4;
            const int m  = m0 + r;
            const int b  = m >> 11, n = m & 2047;
            const int e  = k0 + kc;
            const int h  = e >> 6, dd = e & 63;
            const float* ap = O + (((size_t)((b * Gn + g) * Hn + h) * Nn + n) * 64 + dd);
            float4 av = *(const float4*)ap;
            As[(kc+0)*68 + r] = av.x; As[(kc+1)*68 + r] = av.y;
            As[(kc+2)*68 + r] = av.z; As[(kc+3)*68 + r] = av.w;
            const float* wp = wbase + (size_t)r * 512 + k0 + kc;
            float4 wv = *(const float4*)wp;
            Bs[(kc+0)*68 + r] = wv.x; Bs[(kc+1)*68 + r] = wv.y;
            Bs[(kc+2)*68 + r] = wv.z; Bs[(kc+3)*68 + r] = wv.w;
        }
        __syncthreads();
        #pragma unroll
        for (int kk = 0; kk < 32; ++kk) {
            float4 a = *(const float4*)&As[kk*68 + ty*4];
            float4 b = *(const float4*)&Bs[kk*68 + tx*4];
            float av[4] = {a.x, a.y, a.z, a.w};
            float bv[4] = {b.x, b.y, b.z, b.w};
            #pragma unroll
            for (int i = 0; i < 4; ++i)
                #pragma unroll
                for (int j = 0; j < 4; ++j)
                    acc[i][j] += av[i] * bv[j];
        }
        __syncthreads();
    }

    #pragma unroll
    for (int i = 0; i < 4; ++i) {
        const int m = m0 + ty*4 + i;
        const int b = m >> 11, n = m & 2047;
        float4 val = make_float4(acc[i][0], acc[i][1], acc[i][2], acc[i][3]);
        *(float4*)(out + ((size_t)(b * Gn + g) * Nn + n) * Dn + c0 + tx*4) = val;
    }
}

// ---------------------------------------------------------------------------
extern "C" void kernel_launch(void* const* d_in, const int* in_sizes, int n_in,
                              void* d_out, int out_size, void* d_ws, size_t ws_size,
                              hipStream_t stream)
{
    const float* x     = (const float*)d_in[0];
    const float* Wq    = (const float*)d_in[1];
    const float* Wkv   = (const float*)d_in[2];
    const float* Wout  = (const float*)d_in[3];
    const float* nkv   = (const float*)d_in[4];
    const float* rot_q = (const float*)d_in[5];
    const float* rot_k = (const float*)d_in[6];
    float* out = (float*)d_out;
    char* wsb  = (char*)d_ws;   // needs ~87 MB

    misc_prep<<<dim3((262144 + 8192) / 256), 256, 0, stream>>>(rot_q, rot_k, nkv, wsb);

    qkv_proj<<<dim3(128, 24, 2), 256, 0, stream>>>(x, Wq, Wkv, wsb);

    attn<<<dim3(BGH * 32), 256, 0, stream>>>((const unsigned short*)(wsb + QB_B),
                                             (const unsigned short*)(wsb + KB_B),
                                             (const unsigned short*)(wsb + VT_B),
                                             (float*)(wsb + O_B));

    out_proj<<<dim3(128, 8, 2), 256, 0, stream>>>((const float*)(wsb + O_B), Wout, out);
}

// Round 5
// 331.455 us; speedup vs baseline: 7.4236x; 2.1333x over previous
//
#include <hip/hip_runtime.h>
#include <hip/hip_bf16.h>
#include <math.h>

// Problem constants
#define Bn  4
#define Gn  2
#define Nn  2048
#define Dn  512
#define Hn  8
#define DHn 64
#define N1n 2049
#define NPAD 2112          // keys padded to 33 tiles of 64 (rows >2048 masked)
#define BGH (Bn*Gn*Hn)     // 64

// softmax scale folded with log2(e):  s' = (q.k) * 0.125 * log2e, exp2 domain
#define SCL 0.18033688011112042f

typedef short short8 __attribute__((ext_vector_type(8)));
typedef float float4v __attribute__((ext_vector_type(4)));

// Workspace byte offsets
#define OB_B  ((size_t)0)            // bf16 O  [64][2048][64]   16,777,216
#define QB_B  ((size_t)16777216)     // bf16 Q  [64][2048][64]   16,777,216
#define KB_B  ((size_t)33554432)     // bf16 K  [64][2112][64]   17,301,504
#define VT_B  ((size_t)50855936)     // bf16 V^T[64][64][2112]   17,301,504
#define XB_B  ((size_t)68157440)     // bf16 x  [4][2][2048][512] 16,777,216
#define WC_B  ((size_t)84934656)     // bf16 Wc [2][1536][512]    3,145,728
#define WO_B  ((size_t)88080384)     // bf16 Wo [2][512][512]     1,048,576
#define CSQ_B ((size_t)89128960)     // f32x2 interleaved cos/sin rot_q  1,048,576
#define CSK_B ((size_t)90177536)     // f32x2 interleaved cos/sin rot_k  1,048,576
// end = 91,226,112 B (~87 MiB)

static __device__ __forceinline__ unsigned short f2bf(float x) {
    union { float f; unsigned int u; } c; c.f = x;
    unsigned int r = c.u + 0x7fffu + ((c.u >> 16) & 1u);   // RNE
    return (unsigned short)(r >> 16);
}

static __device__ __forceinline__ void gload16(const void* g, void* l) {
    __builtin_amdgcn_global_load_lds(
        (const __attribute__((address_space(1))) void*)g,
        (__attribute__((address_space(3))) void*)l, 16, 0, 0);
}

// ---------------------------------------------------------------------------
// Kernel 0: prep — bf16 casts of x / Wq|Wkv / Wout, interleaved cos/sin
// tables, null-kv fill.  All segments by flat thread index.
// ---------------------------------------------------------------------------
#define S0 2097152                   // xb float4 slots  (8,388,608 floats / 4)
#define S1 393216                    // Wc  (2 * 196608)
#define S2 131072                    // Wo
#define S3 32768                     // rot_q (4 angles each)
#define S4 32768                     // rot_k
#define S5 8192                      // nulls
__global__ __launch_bounds__(256) void prep(const float* __restrict__ x,
                                            const float* __restrict__ Wq,
                                            const float* __restrict__ Wkv,
                                            const float* __restrict__ Wout,
                                            const float* __restrict__ nkv,
                                            const float* __restrict__ rot_q,
                                            const float* __restrict__ rot_k,
                                            char* __restrict__ wsb)
{
    const int idx = blockIdx.x * 256 + threadIdx.x;
    if (idx < S0) {
        float4 v = ((const float4*)x)[idx];
        ((ushort4*)(wsb + XB_B))[idx] =
            make_ushort4(f2bf(v.x), f2bf(v.y), f2bf(v.z), f2bf(v.w));
    } else if (idx < S0 + S1) {
        const int t = idx - S0;
        const int g = t / 196608;
        const int r4 = t - g * 196608;
        const int j = r4 * 4;
        const int row = j >> 9, k = j & 511;
        const float* src = (row < 512)
            ? (Wq  + ((size_t)g * 512  + row)        * 512 + k)
            : (Wkv + ((size_t)g * 1024 + (row - 512)) * 512 + k);
        float4 v = *(const float4*)src;
        ((ushort4*)(wsb + WC_B))[(size_t)g * 196608 + r4] =
            make_ushort4(f2bf(v.x), f2bf(v.y), f2bf(v.z), f2bf(v.w));
    } else if (idx < S0 + S1 + S2) {
        const int t = idx - (S0 + S1);
        float4 v = ((const float4*)Wout)[t];
        ((ushort4*)(wsb + WO_B))[t] =
            make_ushort4(f2bf(v.x), f2bf(v.y), f2bf(v.z), f2bf(v.w));
    } else if (idx < S0 + S1 + S2 + S3) {
        const int t = idx - (S0 + S1 + S2);
        float4 a = ((const float4*)rot_q)[t];
        float2* cs = (float2*)(wsb + CSQ_B);
        cs[t*4+0] = make_float2(cosf(a.x), sinf(a.x));
        cs[t*4+1] = make_float2(cosf(a.y), sinf(a.y));
        cs[t*4+2] = make_float2(cosf(a.z), sinf(a.z));
        cs[t*4+3] = make_float2(cosf(a.w), sinf(a.w));
    } else if (idx < S0 + S1 + S2 + S3 + S4) {
        const int t = idx - (S0 + S1 + S2 + S3);
        float4 a = ((const float4*)rot_k)[t];
        float2* cs = (float2*)(wsb + CSK_B);
        cs[t*4+0] = make_float2(cosf(a.x), sinf(a.x));
        cs[t*4+1] = make_float2(cosf(a.y), sinf(a.y));
        cs[t*4+2] = make_float2(cosf(a.z), sinf(a.z));
        cs[t*4+3] = make_float2(cosf(a.w), sinf(a.w));
    } else if (idx < S0 + S1 + S2 + S3 + S4 + S5) {
        const int t = idx - (S0 + S1 + S2 + S3 + S4);
        const int s = t >> 12, rem = t & 4095;
        const int bgh = rem >> 6, dh = rem & 63;
        const int gh = bgh & 15;
        if (s == 0)
            ((unsigned short*)(wsb + KB_B))[(size_t)bgh * NPAD * 64 + dh] =
                f2bf(nkv[gh * 64 + dh]);
        else
            ((unsigned short*)(wsb + VT_B))[((size_t)bgh * 64 + dh) * NPAD] =
                f2bf(nkv[1024 + gh * 64 + dh]);
    }
}
#define PREP_BLOCKS ((S0+S1+S2+S3+S4+S5)/256)

// ---------------------------------------------------------------------------
// Kernel 1: bf16 MFMA QKV projection.  C[m][e] = sum_k xb[m][k]*Wc[g][e][k].
// 128x128 tile, BK=64, global_load_lds w/ XOR-swizzled LDS slots.
// Epilogue: rope fused (partner dh^32 = acc[mi][ni^2], same lane), scatter
// to Q (scaled), K (row n+1), V^T layouts in bf16.
// ---------------------------------------------------------------------------
__global__ __launch_bounds__(256) void qkv_proj(char* __restrict__ wsb)
{
    __shared__ alignas(16) unsigned short As[128 * 64];
    __shared__ alignas(16) unsigned short Bs[128 * 64];

    const int g  = blockIdx.z;
    const int m0 = blockIdx.x * 128;    // rows over b*N (per g)
    const int e0 = blockIdx.y * 128;    // cols over 1536
    const int tid = threadIdx.x;
    const int wv = tid >> 6, ln = tid & 63;
    const int l15 = ln & 15, quad = ln >> 4;
    const int wm = (wv & 1) * 64, we = (wv >> 1) * 64;

    const unsigned short* xb = (const unsigned short*)(wsb + XB_B);
    const unsigned short* wc = (const unsigned short*)(wsb + WC_B);

    const int bq = m0 >> 11;                          // batch (block-uniform)
    const size_t arowbase = ((size_t)(bq * Gn + g) * Nn + (m0 & 2047));
    const size_t brockbase = ((size_t)g * 1536 + e0);

    float4v acc[4][4];
    #pragma unroll
    for (int i = 0; i < 4; ++i)
        #pragma unroll
        for (int j = 0; j < 4; ++j) acc[i][j] = (float4v){0.f,0.f,0.f,0.f};

    for (int k0 = 0; k0 < 512; k0 += 64) {
        #pragma unroll
        for (int it = 0; it < 4; ++it) {
            const int sb  = it * 256 + wv * 64;       // wave-uniform slot base
            const int slot = sb + ln;
            const int row = slot >> 3;
            const int c8  = (slot & 7) ^ (row & 7);
            gload16(xb + (arowbase + row) * 512 + k0 + c8 * 8, &As[(size_t)sb * 8]);
            gload16(wc + (brockbase + row) * 512 + k0 + c8 * 8, &Bs[(size_t)sb * 8]);
        }
        __syncthreads();

        #pragma unroll
        for (int kh = 0; kh < 2; ++kh) {
            short8 af[4], bf[4];
            #pragma unroll
            for (int mi = 0; mi < 4; ++mi) {
                const int r = wm + mi * 16 + l15;
                af[mi] = *(const short8*)&As[r * 64 + (((kh*4+quad) ^ (r & 7)) << 3)];
            }
            #pragma unroll
            for (int ni = 0; ni < 4; ++ni) {
                const int r = we + ni * 16 + l15;
                bf[ni] = *(const short8*)&Bs[r * 64 + (((kh*4+quad) ^ (r & 7)) << 3)];
            }
            #pragma unroll
            for (int mi = 0; mi < 4; ++mi)
                #pragma unroll
                for (int ni = 0; ni < 4; ++ni)
                    acc[mi][ni] = __builtin_amdgcn_mfma_f32_16x16x32_bf16(
                        af[mi], bf[ni], acc[mi][ni], 0, 0, 0);
        }
        __syncthreads();
    }

    // Epilogue.  e = e0 + we + ni*16 + l15; sec uniform; h = hbase + (wv>>1).
    const int sec  = e0 >> 9;
    const int hoff = wv >> 1;
    const int nb   = (m0 & 2047) + wm;

    if (sec == 0) {
        unsigned short* Qb = (unsigned short*)(wsb + QB_B);
        const float2* cs = (const float2*)(wsb + CSQ_B);
        const int bgh = (bq * Gn + g) * Hn + ((e0 & 511) >> 6) + hoff;
        #pragma unroll
        for (int mi = 0; mi < 4; ++mi) {
            #pragma unroll
            for (int r = 0; r < 4; ++r) {
                const int n = nb + mi * 16 + quad * 4 + r;
                unsigned short* qrow = Qb + ((size_t)bgh * Nn + n) * 64;
                #pragma unroll
                for (int ni = 0; ni < 4; ++ni) {
                    const int dh = ni * 16 + l15;
                    float2 c = cs[n * 64 + dh];
                    const float v = acc[mi][ni][r];
                    const float p = acc[mi][ni ^ 2][r];
                    const float rh = (ni < 2) ? -p : p;
                    qrow[dh] = f2bf((v * c.x + rh * c.y) * SCL);
                }
            }
        }
    } else if (sec == 1) {
        unsigned short* Kb = (unsigned short*)(wsb + KB_B);
        const float2* cs = (const float2*)(wsb + CSK_B);
        const int bgh = (bq * Gn + g) * Hn + ((e0 - 512) >> 6) + hoff;
        #pragma unroll
        for (int mi = 0; mi < 4; ++mi) {
            #pragma unroll
            for (int r = 0; r < 4; ++r) {
                const int n = nb + mi * 16 + quad * 4 + r;
                unsigned short* krow = Kb + ((size_t)bgh * NPAD + n + 1) * 64;
                #pragma unroll
                for (int ni = 0; ni < 4; ++ni) {
                    const int dh = ni * 16 + l15;
                    float2 c = cs[n * 64 + dh];
                    const float v = acc[mi][ni][r];
                    const float p = acc[mi][ni ^ 2][r];
                    const float rh = (ni < 2) ? -p : p;
                    krow[dh] = f2bf(v * c.x + rh * c.y);
                }
            }
        }
    } else {
        unsigned short* Vt = (unsigned short*)(wsb + VT_B);
        const int bgh = (bq * Gn + g) * Hn + ((e0 - 1024) >> 6) + hoff;
        #pragma unroll
        for (int mi = 0; mi < 4; ++mi) {
            #pragma unroll
            for (int ni = 0; ni < 4; ++ni) {
                const int dh = ni * 16 + l15;
                unsigned short* vrow = Vt + ((size_t)bgh * 64 + dh) * NPAD
                                         + nb + mi * 16 + quad * 4 + 1;
                #pragma unroll
                for (int r = 0; r < 4; ++r)
                    vrow[r] = f2bf(acc[mi][ni][r]);
            }
        }
    }
}

// ---------------------------------------------------------------------------
// Kernel 2: bf16 MFMA flash attention (verified R3 structure; O written bf16
// head-major for the MFMA out-projection).
// ---------------------------------------------------------------------------
__global__ __launch_bounds__(256, 4) void attn(const unsigned short* __restrict__ Qb,
                                               const unsigned short* __restrict__ Kb,
                                               const unsigned short* __restrict__ Vt,
                                               unsigned short* __restrict__ Ob)
{
    __shared__ alignas(16) unsigned short Ks[64 * 72];
    __shared__ alignas(16) unsigned short Vs[64 * 72];
    __shared__ alignas(16) unsigned short Ps[4 * 16 * 72];

    const int tid  = threadIdx.x;
    const int bid  = blockIdx.x;
    const int bgh  = bid >> 5;
    const int q0   = (bid & 31) * 64;
    const int wv   = tid >> 6;
    const int ln   = tid & 63;
    const int l15  = ln & 15;
    const int quad = ln >> 4;

    const int q = q0 + wv * 16 + l15;
    const unsigned short* qrow = Qb + ((size_t)bgh * Nn + q) * 64;
    short8 bq0 = *(const short8*)(qrow + quad * 8);
    short8 bq1 = *(const short8*)(qrow + 32 + quad * 8);

    float4v Oa[4];
    #pragma unroll
    for (int nt = 0; nt < 4; ++nt) Oa[nt] = (float4v){0.f, 0.f, 0.f, 0.f};
    float mrun = -INFINITY, lrun = 0.f;

    const unsigned short* kbase = Kb + (size_t)bgh * NPAD * 64;
    const unsigned short* vbase = Vt + (size_t)bgh * 64 * NPAD;
    unsigned short* Pw = Ps + wv * 16 * 72;

    for (int kt = 0; kt <= 2048; kt += 64) {
        #pragma unroll
        for (int c = 0; c < 2; ++c) {
            const int chunk = tid + c * 256;
            const int row = chunk >> 3, c8 = chunk & 7;
            *(float4*)&Ks[row * 72 + c8 * 8] =
                *(const float4*)(kbase + (size_t)(kt + row) * 64 + c8 * 8);
            *(float4*)&Vs[row * 72 + c8 * 8] =
                *(const float4*)(vbase + (size_t)row * NPAD + kt + c8 * 8);
        }
        __syncthreads();

        float4v stv[4];
        #pragma unroll
        for (int mt = 0; mt < 4; ++mt) {
            const unsigned short* krow = &Ks[(mt * 16 + l15) * 72];
            short8 a0 = *(const short8*)(krow + quad * 8);
            short8 a1 = *(const short8*)(krow + 32 + quad * 8);
            float4v z = {0.f, 0.f, 0.f, 0.f};
            z = __builtin_amdgcn_mfma_f32_16x16x32_bf16(a0, bq0, z, 0, 0, 0);
            z = __builtin_amdgcn_mfma_f32_16x16x32_bf16(a1, bq1, z, 0, 0, 0);
            stv[mt] = z;
        }
        if (kt == 2048) {
            #pragma unroll
            for (int mt = 0; mt < 4; ++mt)
                #pragma unroll
                for (int r = 0; r < 4; ++r)
                    if (kt + mt * 16 + quad * 4 + r > 2048) stv[mt][r] = -INFINITY;
        }

        float tmax = -INFINITY;
        #pragma unroll
        for (int mt = 0; mt < 4; ++mt)
            #pragma unroll
            for (int r = 0; r < 4; ++r) tmax = fmaxf(tmax, stv[mt][r]);
        tmax = fmaxf(tmax, __shfl_xor(tmax, 16));
        tmax = fmaxf(tmax, __shfl_xor(tmax, 32));
        const float newm = fmaxf(mrun, tmax);
        const float corr = __builtin_amdgcn_exp2f(mrun - newm);

        float psum = 0.f;
        #pragma unroll
        for (int mt = 0; mt < 4; ++mt) {
            float pv[4];
            #pragma unroll
            for (int r = 0; r < 4; ++r) {
                pv[r] = __builtin_amdgcn_exp2f(stv[mt][r] - newm);
                psum += pv[r];
            }
            ushort4 w = { f2bf(pv[0]), f2bf(pv[1]), f2bf(pv[2]), f2bf(pv[3]) };
            *(ushort4*)&Pw[l15 * 72 + mt * 16 + quad * 4] = w;
        }
        psum += __shfl_xor(psum, 16);
        psum += __shfl_xor(psum, 32);
        lrun = lrun * corr + psum;
        mrun = newm;

        const float c0 = __shfl(corr, quad * 4 + 0);
        const float c1 = __shfl(corr, quad * 4 + 1);
        const float c2 = __shfl(corr, quad * 4 + 2);
        const float c3 = __shfl(corr, quad * 4 + 3);
        #pragma unroll
        for (int nt = 0; nt < 4; ++nt) {
            Oa[nt][0] *= c0; Oa[nt][1] *= c1; Oa[nt][2] *= c2; Oa[nt][3] *= c3;
        }

        short8 ap0 = *(const short8*)&Pw[l15 * 72 + quad * 8];
        short8 ap1 = *(const short8*)&Pw[l15 * 72 + 32 + quad * 8];
        #pragma unroll
        for (int nt = 0; nt < 4; ++nt) {
            const unsigned short* vrow = &Vs[(nt * 16 + l15) * 72];
            short8 b0 = *(const short8*)(vrow + quad * 8);
            short8 b1 = *(const short8*)(vrow + 32 + quad * 8);
            Oa[nt] = __builtin_amdgcn_mfma_f32_16x16x32_bf16(ap0, b0, Oa[nt], 0, 0, 0);
            Oa[nt] = __builtin_amdgcn_mfma_f32_16x16x32_bf16(ap1, b1, Oa[nt], 0, 0, 0);
        }
        __syncthreads();
    }

    const float inv = 1.f / lrun;
    const float i0 = __shfl(inv, quad * 4 + 0);
    const float i1 = __shfl(inv, quad * 4 + 1);
    const float i2 = __shfl(inv, quad * 4 + 2);
    const float i3 = __shfl(inv, quad * 4 + 3);
    unsigned short* obase = Ob + ((size_t)bgh * Nn + q0 + wv * 16) * 64;
    #pragma unroll
    for (int nt = 0; nt < 4; ++nt) {
        obase[(quad * 4 + 0) * 64 + nt * 16 + l15] = f2bf(Oa[nt][0] * i0);
        obase[(quad * 4 + 1) * 64 + nt * 16 + l15] = f2bf(Oa[nt][1] * i1);
        obase[(quad * 4 + 2) * 64 + nt * 16 + l15] = f2bf(Oa[nt][2] * i2);
        obase[(quad * 4 + 3) * 64 + nt * 16 + l15] = f2bf(Oa[nt][3] * i3);
    }
}

// ---------------------------------------------------------------------------
// Kernel 3: bf16 MFMA output projection.
// out[m][dcol] = sum_e Ob[m][e] * Wo[g][dcol][e].  Ob head-major: for k-tile
// k0 (64-aligned) the whole tile lies in head h=k0>>6 -> contiguous slab.
// ---------------------------------------------------------------------------
__global__ __launch_bounds__(256) void out_proj(const char* __restrict__ wsb,
                                                float* __restrict__ out)
{
    __shared__ alignas(16) unsigned short As[128 * 64];
    __shared__ alignas(16) unsigned short Bs[128 * 64];

    const int g  = blockIdx.z;
    const int m0 = blockIdx.x * 128;
    const int c0 = blockIdx.y * 128;
    const int tid = threadIdx.x;
    const int wv = tid >> 6, ln = tid & 63;
    const int l15 = ln & 15, quad = ln >> 4;
    const int wm = (wv & 1) * 64, we = (wv >> 1) * 64;

    const unsigned short* Ob = (const unsigned short*)(wsb + OB_B);
    const unsigned short* Wo = (const unsigned short*)(wsb + WO_B);

    const int bq = m0 >> 11;
    const int n0 = m0 & 2047;

    float4v acc[4][4];
    #pragma unroll
    for (int i = 0; i < 4; ++i)
        #pragma unroll
        for (int j = 0; j < 4; ++j) acc[i][j] = (float4v){0.f,0.f,0.f,0.f};

    for (int k0 = 0; k0 < 512; k0 += 64) {
        const int h = k0 >> 6;
        const unsigned short* abase =
            Ob + (((size_t)(bq * Gn + g) * Hn + h) * Nn + n0) * 64;
        const unsigned short* bbase =
            Wo + ((size_t)g * 512 + c0) * 512 + k0;
        #pragma unroll
        for (int it = 0; it < 4; ++it) {
            const int sb  = it * 256 + wv * 64;
            const int slot = sb + ln;
            const int row = slot >> 3;
            const int c8  = (slot & 7) ^ (row & 7);
            gload16(abase + (size_t)row * 64  + c8 * 8, &As[(size_t)sb * 8]);
            gload16(bbase + (size_t)row * 512 + c8 * 8, &Bs[(size_t)sb * 8]);
        }
        __syncthreads();

        #pragma unroll
        for (int kh = 0; kh < 2; ++kh) {
            short8 af[4], bf[4];
            #pragma unroll
            for (int mi = 0; mi < 4; ++mi) {
                const int r = wm + mi * 16 + l15;
                af[mi] = *(const short8*)&As[r * 64 + (((kh*4+quad) ^ (r & 7)) << 3)];
            }
            #pragma unroll
            for (int ni = 0; ni < 4; ++ni) {
                const int r = we + ni * 16 + l15;
                bf[ni] = *(const short8*)&Bs[r * 64 + (((kh*4+quad) ^ (r & 7)) << 3)];
            }
            #pragma unroll
            for (int mi = 0; mi < 4; ++mi)
                #pragma unroll
                for (int ni = 0; ni < 4; ++ni)
                    acc[mi][ni] = __builtin_amdgcn_mfma_f32_16x16x32_bf16(
                        af[mi], bf[ni], acc[mi][ni], 0, 0, 0);
        }
        __syncthreads();
    }

    #pragma unroll
    for (int mi = 0; mi < 4; ++mi) {
        #pragma unroll
        for (int r = 0; r < 4; ++r) {
            const int n = n0 + wm + mi * 16 + quad * 4 + r;
            float* orow = out + ((size_t)(bq * Gn + g) * Nn + n) * Dn;
            #pragma unroll
            for (int ni = 0; ni < 4; ++ni)
                orow[c0 + we + ni * 16 + l15] = acc[mi][ni][r];
        }
    }
}

// ---------------------------------------------------------------------------
extern "C" void kernel_launch(void* const* d_in, const int* in_sizes, int n_in,
                              void* d_out, int out_size, void* d_ws, size_t ws_size,
                              hipStream_t stream)
{
    const float* x     = (const float*)d_in[0];
    const float* Wq    = (const float*)d_in[1];
    const float* Wkv   = (const float*)d_in[2];
    const float* Wout  = (const float*)d_in[3];
    const float* nkv   = (const float*)d_in[4];
    const float* rot_q = (const float*)d_in[5];
    const float* rot_k = (const float*)d_in[6];
    float* out = (float*)d_out;
    char* wsb  = (char*)d_ws;   // needs ~87 MB

    prep<<<dim3(PREP_BLOCKS), 256, 0, stream>>>(x, Wq, Wkv, Wout, nkv,
                                                rot_q, rot_k, wsb);

    qkv_proj<<<dim3(64, 12, 2), 256, 0, stream>>>(wsb);

    attn<<<dim3(BGH * 32), 256, 0, stream>>>((const unsigned short*)(wsb + QB_B),
                                             (const unsigned short*)(wsb + KB_B),
                                             (const unsigned short*)(wsb + VT_B),
                                             (unsigned short*)(wsb + OB_B));

    out_proj<<<dim3(64, 4, 2), 256, 0, stream>>>(wsb, out);
}

// Round 6
// 282.760 us; speedup vs baseline: 8.7021x; 1.1722x over previous
//
#include <hip/hip_runtime.h>
#include <hip/hip_bf16.h>
#include <math.h>

// Problem constants
#define Bn  4
#define Gn  2
#define Nn  2048
#define Dn  512
#define Hn  8
#define DHn 64
#define N1n 2049
#define NPAD 2112          // keys padded to 33 tiles of 64 (rows >2048 masked)
#define BGH (Bn*Gn*Hn)     // 64

// softmax scale folded with log2(e):  s' = (q.k) * 0.125 * log2e, exp2 domain
#define SCL 0.18033688011112042f

typedef short short8 __attribute__((ext_vector_type(8)));
typedef float float4v __attribute__((ext_vector_type(4)));

// Workspace byte offsets
#define OB_B  ((size_t)0)            // bf16 O  [64][2048][64]   16,777,216
#define QB_B  ((size_t)16777216)     // bf16 Q  [64][2048][64]   16,777,216
#define KB_B  ((size_t)33554432)     // bf16 K  [64][2112][64]   17,301,504
#define VT_B  ((size_t)50855936)     // bf16 V^T[64][64][2112]   17,301,504
#define XB_B  ((size_t)68157440)     // bf16 x  [4][2][2048][512] 16,777,216
#define WC_B  ((size_t)84934656)     // bf16 Wc [2][1536][512]    3,145,728
#define WO_B  ((size_t)88080384)     // bf16 Wo [2][512][512]     1,048,576
#define CSQ_B ((size_t)89128960)     // f32x2 interleaved cos/sin rot_q  1,048,576
#define CSK_B ((size_t)90177536)     // f32x2 interleaved cos/sin rot_k  1,048,576
// end = 91,226,112 B (~87 MiB)

static __device__ __forceinline__ unsigned short f2bf(float x) {
    union { float f; unsigned int u; } c; c.f = x;
    unsigned int r = c.u + 0x7fffu + ((c.u >> 16) & 1u);   // RNE
    return (unsigned short)(r >> 16);
}

// pack two floats to bf16x2 (round-half-up) in one v_perm
static __device__ __forceinline__ unsigned int pk2bf(float lo, float hi) {
    union { float f; unsigned int u; } a, b; a.f = lo; b.f = hi;
    return __builtin_amdgcn_perm(b.u + 0x8000u, a.u + 0x8000u, 0x07060302u);
}

static __device__ __forceinline__ void gload16(const void* g, void* l) {
    __builtin_amdgcn_global_load_lds(
        (const __attribute__((address_space(1))) void*)g,
        (__attribute__((address_space(3))) void*)l, 16, 0, 0);
}

// ---------------------------------------------------------------------------
// Kernel 0: prep — bf16 casts of x / Wq|Wkv / Wout, interleaved cos/sin
// tables, null-kv fill.  All segments by flat thread index.
// ---------------------------------------------------------------------------
#define S0 2097152                   // xb float4 slots  (8,388,608 floats / 4)
#define S1 393216                    // Wc  (2 * 196608)
#define S2 131072                    // Wo
#define S3 32768                     // rot_q (4 angles each)
#define S4 32768                     // rot_k
#define S5 8192                      // nulls
__global__ __launch_bounds__(256) void prep(const float* __restrict__ x,
                                            const float* __restrict__ Wq,
                                            const float* __restrict__ Wkv,
                                            const float* __restrict__ Wout,
                                            const float* __restrict__ nkv,
                                            const float* __restrict__ rot_q,
                                            const float* __restrict__ rot_k,
                                            char* __restrict__ wsb)
{
    const int idx = blockIdx.x * 256 + threadIdx.x;
    if (idx < S0) {
        float4 v = ((const float4*)x)[idx];
        ((ushort4*)(wsb + XB_B))[idx] =
            make_ushort4(f2bf(v.x), f2bf(v.y), f2bf(v.z), f2bf(v.w));
    } else if (idx < S0 + S1) {
        const int t = idx - S0;
        const int g = t / 196608;
        const int r4 = t - g * 196608;
        const int j = r4 * 4;
        const int row = j >> 9, k = j & 511;
        const float* src = (row < 512)
            ? (Wq  + ((size_t)g * 512  + row)        * 512 + k)
            : (Wkv + ((size_t)g * 1024 + (row - 512)) * 512 + k);
        float4 v = *(const float4*)src;
        ((ushort4*)(wsb + WC_B))[(size_t)g * 196608 + r4] =
            make_ushort4(f2bf(v.x), f2bf(v.y), f2bf(v.z), f2bf(v.w));
    } else if (idx < S0 + S1 + S2) {
        const int t = idx - (S0 + S1);
        float4 v = ((const float4*)Wout)[t];
        ((ushort4*)(wsb + WO_B))[t] =
            make_ushort4(f2bf(v.x), f2bf(v.y), f2bf(v.z), f2bf(v.w));
    } else if (idx < S0 + S1 + S2 + S3) {
        const int t = idx - (S0 + S1 + S2);
        float4 a = ((const float4*)rot_q)[t];
        float2* cs = (float2*)(wsb + CSQ_B);
        cs[t*4+0] = make_float2(cosf(a.x), sinf(a.x));
        cs[t*4+1] = make_float2(cosf(a.y), sinf(a.y));
        cs[t*4+2] = make_float2(cosf(a.z), sinf(a.z));
        cs[t*4+3] = make_float2(cosf(a.w), sinf(a.w));
    } else if (idx < S0 + S1 + S2 + S3 + S4) {
        const int t = idx - (S0 + S1 + S2 + S3);
        float4 a = ((const float4*)rot_k)[t];
        float2* cs = (float2*)(wsb + CSK_B);
        cs[t*4+0] = make_float2(cosf(a.x), sinf(a.x));
        cs[t*4+1] = make_float2(cosf(a.y), sinf(a.y));
        cs[t*4+2] = make_float2(cosf(a.z), sinf(a.z));
        cs[t*4+3] = make_float2(cosf(a.w), sinf(a.w));
    } else if (idx < S0 + S1 + S2 + S3 + S4 + S5) {
        const int t = idx - (S0 + S1 + S2 + S3 + S4);
        const int s = t >> 12, rem = t & 4095;
        const int bgh = rem >> 6, dh = rem & 63;
        const int gh = bgh & 15;
        if (s == 0)
            ((unsigned short*)(wsb + KB_B))[(size_t)bgh * NPAD * 64 + dh] =
                f2bf(nkv[gh * 64 + dh]);
        else
            ((unsigned short*)(wsb + VT_B))[((size_t)bgh * 64 + dh) * NPAD] =
                f2bf(nkv[1024 + gh * 64 + dh]);
    }
}
#define PREP_BLOCKS ((S0+S1+S2+S3+S4+S5)/256)

// ---------------------------------------------------------------------------
// Kernel 1: bf16 MFMA QKV projection (verified R5 structure).
// ---------------------------------------------------------------------------
__global__ __launch_bounds__(256) void qkv_proj(char* __restrict__ wsb)
{
    __shared__ alignas(16) unsigned short As[128 * 64];
    __shared__ alignas(16) unsigned short Bs[128 * 64];

    const int g  = blockIdx.z;
    const int m0 = blockIdx.x * 128;    // rows over b*N (per g)
    const int e0 = blockIdx.y * 128;    // cols over 1536
    const int tid = threadIdx.x;
    const int wv = tid >> 6, ln = tid & 63;
    const int l15 = ln & 15, quad = ln >> 4;
    const int wm = (wv & 1) * 64, we = (wv >> 1) * 64;

    const unsigned short* xb = (const unsigned short*)(wsb + XB_B);
    const unsigned short* wc = (const unsigned short*)(wsb + WC_B);

    const int bq = m0 >> 11;                          // batch (block-uniform)
    const size_t arowbase = ((size_t)(bq * Gn + g) * Nn + (m0 & 2047));
    const size_t brockbase = ((size_t)g * 1536 + e0);

    float4v acc[4][4];
    #pragma unroll
    for (int i = 0; i < 4; ++i)
        #pragma unroll
        for (int j = 0; j < 4; ++j) acc[i][j] = (float4v){0.f,0.f,0.f,0.f};

    for (int k0 = 0; k0 < 512; k0 += 64) {
        #pragma unroll
        for (int it = 0; it < 4; ++it) {
            const int sb  = it * 256 + wv * 64;       // wave-uniform slot base
            const int slot = sb + ln;
            const int row = slot >> 3;
            const int c8  = (slot & 7) ^ (row & 7);
            gload16(xb + (arowbase + row) * 512 + k0 + c8 * 8, &As[(size_t)sb * 8]);
            gload16(wc + (brockbase + row) * 512 + k0 + c8 * 8, &Bs[(size_t)sb * 8]);
        }
        __syncthreads();

        #pragma unroll
        for (int kh = 0; kh < 2; ++kh) {
            short8 af[4], bf[4];
            #pragma unroll
            for (int mi = 0; mi < 4; ++mi) {
                const int r = wm + mi * 16 + l15;
                af[mi] = *(const short8*)&As[r * 64 + (((kh*4+quad) ^ (r & 7)) << 3)];
            }
            #pragma unroll
            for (int ni = 0; ni < 4; ++ni) {
                const int r = we + ni * 16 + l15;
                bf[ni] = *(const short8*)&Bs[r * 64 + (((kh*4+quad) ^ (r & 7)) << 3)];
            }
            #pragma unroll
            for (int mi = 0; mi < 4; ++mi)
                #pragma unroll
                for (int ni = 0; ni < 4; ++ni)
                    acc[mi][ni] = __builtin_amdgcn_mfma_f32_16x16x32_bf16(
                        af[mi], bf[ni], acc[mi][ni], 0, 0, 0);
        }
        __syncthreads();
    }

    // Epilogue.  e = e0 + we + ni*16 + l15; sec uniform; h = hbase + (wv>>1).
    const int sec  = e0 >> 9;
    const int hoff = wv >> 1;
    const int nb   = (m0 & 2047) + wm;

    if (sec == 0) {
        unsigned short* Qb = (unsigned short*)(wsb + QB_B);
        const float2* cs = (const float2*)(wsb + CSQ_B);
        const int bgh = (bq * Gn + g) * Hn + ((e0 & 511) >> 6) + hoff;
        #pragma unroll
        for (int mi = 0; mi < 4; ++mi) {
            #pragma unroll
            for (int r = 0; r < 4; ++r) {
                const int n = nb + mi * 16 + quad * 4 + r;
                unsigned short* qrow = Qb + ((size_t)bgh * Nn + n) * 64;
                #pragma unroll
                for (int ni = 0; ni < 4; ++ni) {
                    const int dh = ni * 16 + l15;
                    float2 c = cs[n * 64 + dh];
                    const float v = acc[mi][ni][r];
                    const float p = acc[mi][ni ^ 2][r];
                    const float rh = (ni < 2) ? -p : p;
                    qrow[dh] = f2bf((v * c.x + rh * c.y) * SCL);
                }
            }
        }
    } else if (sec == 1) {
        unsigned short* Kb = (unsigned short*)(wsb + KB_B);
        const float2* cs = (const float2*)(wsb + CSK_B);
        const int bgh = (bq * Gn + g) * Hn + ((e0 - 512) >> 6) + hoff;
        #pragma unroll
        for (int mi = 0; mi < 4; ++mi) {
            #pragma unroll
            for (int r = 0; r < 4; ++r) {
                const int n = nb + mi * 16 + quad * 4 + r;
                unsigned short* krow = Kb + ((size_t)bgh * NPAD + n + 1) * 64;
                #pragma unroll
                for (int ni = 0; ni < 4; ++ni) {
                    const int dh = ni * 16 + l15;
                    float2 c = cs[n * 64 + dh];
                    const float v = acc[mi][ni][r];
                    const float p = acc[mi][ni ^ 2][r];
                    const float rh = (ni < 2) ? -p : p;
                    krow[dh] = f2bf(v * c.x + rh * c.y);
                }
            }
        }
    } else {
        unsigned short* Vt = (unsigned short*)(wsb + VT_B);
        const int bgh = (bq * Gn + g) * Hn + ((e0 - 1024) >> 6) + hoff;
        #pragma unroll
        for (int mi = 0; mi < 4; ++mi) {
            #pragma unroll
            for (int ni = 0; ni < 4; ++ni) {
                const int dh = ni * 16 + l15;
                unsigned short* vrow = Vt + ((size_t)bgh * 64 + dh) * NPAD
                                         + nb + mi * 16 + quad * 4 + 1;
                #pragma unroll
                for (int r = 0; r < 4; ++r)
                    vrow[r] = f2bf(acc[mi][ni][r]);
            }
        }
    }
}

// ---------------------------------------------------------------------------
// Kernel 2: bf16 MFMA flash attention v2.
//   - 4 waves x 32 q-rows = 128 q per block; 64-key tiles (33 iters).
//   - no online max (scores bounded: exp2 in fp32 cannot overflow), l
//     accumulated per-lane, reduced once at the end.
//   - K/V staged via global_load_lds, XOR-swizzled columns (<=2-way LDS).
//   - P packed to bf16 via v_perm (round-half-up), per-wave LDS region.
// ---------------------------------------------------------------------------
__global__ __launch_bounds__(256, 4) void attn(const unsigned short* __restrict__ Qb,
                                               const unsigned short* __restrict__ Kb,
                                               const unsigned short* __restrict__ Vt,
                                               unsigned short* __restrict__ Ob)
{
    __shared__ alignas(16) unsigned short Ks[64 * 64];   // [key][dh]  swizzled
    __shared__ alignas(16) unsigned short Vs[64 * 64];   // [dh][key]  swizzled
    __shared__ alignas(16) unsigned short Ps[4 * 32 * 64]; // per-wave [q][key] swizzled

    const int tid  = threadIdx.x;
    const int bid  = blockIdx.x;
    const int bgh  = bid >> 4;           // 16 consecutive blocks share a head
    const int q0   = (bid & 15) * 128;
    const int wv   = tid >> 6;
    const int ln   = tid & 63;
    const int l15  = ln & 15;
    const int quad = ln >> 4;

    // Q B-frags: bq[qs][kh], lane holds Q[q = q0+wv*32+qs*16+l15][kh*32+quad*8 ..]
    short8 bq[2][2];
    #pragma unroll
    for (int qs = 0; qs < 2; ++qs) {
        const unsigned short* qrow =
            Qb + ((size_t)bgh * Nn + q0 + wv * 32 + qs * 16 + l15) * 64;
        bq[qs][0] = *(const short8*)(qrow + quad * 8);
        bq[qs][1] = *(const short8*)(qrow + 32 + quad * 8);
    }

    float4v Oa[2][4];
    #pragma unroll
    for (int ms = 0; ms < 2; ++ms)
        #pragma unroll
        for (int nt = 0; nt < 4; ++nt) Oa[ms][nt] = (float4v){0.f,0.f,0.f,0.f};
    float lr[2] = {0.f, 0.f};

    const unsigned short* kptr = Kb + (size_t)bgh * NPAD * 64;   // += 4096/iter
    const unsigned short* vptr = Vt + (size_t)bgh * 64 * NPAD;   // += 64/iter
    unsigned short* Pw = Ps + wv * 32 * 64;

    for (int kt = 0; kt <= 2048; kt += 64) {
        // stage K tile [64 keys][64 dh] and V tile [64 dh][64 keys]
        #pragma unroll
        for (int it = 0; it < 2; ++it) {
            const int sb  = it * 256 + wv * 64;      // wave-uniform slot base
            const int slot = sb + ln;
            const int row = slot >> 3;
            const int c8  = (slot & 7) ^ (row & 7);
            gload16(kptr + (size_t)row * 64   + c8 * 8, &Ks[(size_t)sb * 8]);
            gload16(vptr + (size_t)row * NPAD + c8 * 8, &Vs[(size_t)sb * 8]);
        }
        __syncthreads();

        // S^T per 16-key subtile: exp2 -> pack -> store to Pw
        #pragma unroll
        for (int mt = 0; mt < 4; ++mt) {
            const int rk = mt * 16 + l15;            // key row in tile
            short8 af0 = *(const short8*)&Ks[rk * 64 + (((    quad) ^ (rk & 7)) << 3)];
            short8 af1 = *(const short8*)&Ks[rk * 64 + (((4 + quad) ^ (rk & 7)) << 3)];
            #pragma unroll
            for (int qs = 0; qs < 2; ++qs) {
                float4v z = {0.f, 0.f, 0.f, 0.f};
                z = __builtin_amdgcn_mfma_f32_16x16x32_bf16(af0, bq[qs][0], z, 0, 0, 0);
                z = __builtin_amdgcn_mfma_f32_16x16x32_bf16(af1, bq[qs][1], z, 0, 0, 0);
                if (kt == 2048) {                    // mask pad keys (> 2048)
                    #pragma unroll
                    for (int r = 0; r < 4; ++r)
                        if (mt * 16 + quad * 4 + r > 0) z[r] = -INFINITY;
                }
                float pv0 = __builtin_amdgcn_exp2f(z[0]);
                float pv1 = __builtin_amdgcn_exp2f(z[1]);
                float pv2 = __builtin_amdgcn_exp2f(z[2]);
                float pv3 = __builtin_amdgcn_exp2f(z[3]);
                lr[qs] += (pv0 + pv1) + (pv2 + pv3);
                uint2 w = make_uint2(pk2bf(pv0, pv1), pk2bf(pv2, pv3));
                const int rq = qs * 16 + l15;
                const int cq = mt * 2 + (quad >> 1);
                *(uint2*)&Pw[rq * 64 + ((cq ^ (rq & 7)) << 3) + (quad & 1) * 4] = w;
            }
        }

        // PV: A = P (m=q, k=key), B = V rows (k=key, n=dh)
        short8 ap[2][2];
        #pragma unroll
        for (int ms = 0; ms < 2; ++ms) {
            const int rq = ms * 16 + l15;
            ap[ms][0] = *(const short8*)&Pw[rq * 64 + (((    quad) ^ (rq & 7)) << 3)];
            ap[ms][1] = *(const short8*)&Pw[rq * 64 + (((4 + quad) ^ (rq & 7)) << 3)];
        }
        #pragma unroll
        for (int nt = 0; nt < 4; ++nt) {
            const int rv = nt * 16 + l15;
            short8 b0 = *(const short8*)&Vs[rv * 64 + (((    quad) ^ (rv & 7)) << 3)];
            short8 b1 = *(const short8*)&Vs[rv * 64 + (((4 + quad) ^ (rv & 7)) << 3)];
            #pragma unroll
            for (int ms = 0; ms < 2; ++ms) {
                Oa[ms][nt] = __builtin_amdgcn_mfma_f32_16x16x32_bf16(ap[ms][0], b0, Oa[ms][nt], 0, 0, 0);
                Oa[ms][nt] = __builtin_amdgcn_mfma_f32_16x16x32_bf16(ap[ms][1], b1, Oa[ms][nt], 0, 0, 0);
            }
        }
        __syncthreads();

        kptr += 64 * 64;
        vptr += 64;
    }

    // final l reduce across quads, then normalize + write O (bf16 head-major)
    float inv[2];
    #pragma unroll
    for (int qs = 0; qs < 2; ++qs) {
        float l = lr[qs];
        l += __shfl_xor(l, 16);
        l += __shfl_xor(l, 32);
        inv[qs] = 1.f / l;
    }
    unsigned short* obase = Ob + ((size_t)bgh * Nn + q0 + wv * 32) * 64;
    #pragma unroll
    for (int ms = 0; ms < 2; ++ms) {
        #pragma unroll
        for (int r = 0; r < 4; ++r) {
            const float iv = __shfl(inv[ms], quad * 4 + r);
            #pragma unroll
            for (int nt = 0; nt < 4; ++nt)
                obase[(ms * 16 + quad * 4 + r) * 64 + nt * 16 + l15] =
                    f2bf(Oa[ms][nt][r] * iv);
        }
    }
}

// ---------------------------------------------------------------------------
// Kernel 3: bf16 MFMA output projection (verified R5 structure).
// ---------------------------------------------------------------------------
__global__ __launch_bounds__(256) void out_proj(const char* __restrict__ wsb,
                                                float* __restrict__ out)
{
    __shared__ alignas(16) unsigned short As[128 * 64];
    __shared__ alignas(16) unsigned short Bs[128 * 64];

    const int g  = blockIdx.z;
    const int m0 = blockIdx.x * 128;
    const int c0 = blockIdx.y * 128;
    const int tid = threadIdx.x;
    const int wv = tid >> 6, ln = tid & 63;
    const int l15 = ln & 15, quad = ln >> 4;
    const int wm = (wv & 1) * 64, we = (wv >> 1) * 64;

    const unsigned short* Ob = (const unsigned short*)(wsb + OB_B);
    const unsigned short* Wo = (const unsigned short*)(wsb + WO_B);

    const int bq = m0 >> 11;
    const int n0 = m0 & 2047;

    float4v acc[4][4];
    #pragma unroll
    for (int i = 0; i < 4; ++i)
        #pragma unroll
        for (int j = 0; j < 4; ++j) acc[i][j] = (float4v){0.f,0.f,0.f,0.f};

    for (int k0 = 0; k0 < 512; k0 += 64) {
        const int h = k0 >> 6;
        const unsigned short* abase =
            Ob + (((size_t)(bq * Gn + g) * Hn + h) * Nn + n0) * 64;
        const unsigned short* bbase =
            Wo + ((size_t)g * 512 + c0) * 512 + k0;
        #pragma unroll
        for (int it = 0; it < 4; ++it) {
            const int sb  = it * 256 + wv * 64;
            const int slot = sb + ln;
            const int row = slot >> 3;
            const int c8  = (slot & 7) ^ (row & 7);
            gload16(abase + (size_t)row * 64  + c8 * 8, &As[(size_t)sb * 8]);
            gload16(bbase + (size_t)row * 512 + c8 * 8, &Bs[(size_t)sb * 8]);
        }
        __syncthreads();

        #pragma unroll
        for (int kh = 0; kh < 2; ++kh) {
            short8 af[4], bf[4];
            #pragma unroll
            for (int mi = 0; mi < 4; ++mi) {
                const int r = wm + mi * 16 + l15;
                af[mi] = *(const short8*)&As[r * 64 + (((kh*4+quad) ^ (r & 7)) << 3)];
            }
            #pragma unroll
            for (int ni = 0; ni < 4; ++ni) {
                const int r = we + ni * 16 + l15;
                bf[ni] = *(const short8*)&Bs[r * 64 + (((kh*4+quad) ^ (r & 7)) << 3)];
            }
            #pragma unroll
            for (int mi = 0; mi < 4; ++mi)
                #pragma unroll
                for (int ni = 0; ni < 4; ++ni)
                    acc[mi][ni] = __builtin_amdgcn_mfma_f32_16x16x32_bf16(
                        af[mi], bf[ni], acc[mi][ni], 0, 0, 0);
        }
        __syncthreads();
    }

    #pragma unroll
    for (int mi = 0; mi < 4; ++mi) {
        #pragma unroll
        for (int r = 0; r < 4; ++r) {
            const int n = n0 + wm + mi * 16 + quad * 4 + r;
            float* orow = out + ((size_t)(bq * Gn + g) * Nn + n) * Dn;
            #pragma unroll
            for (int ni = 0; ni < 4; ++ni)
                orow[c0 + we + ni * 16 + l15] = acc[mi][ni][r];
        }
    }
}

// ---------------------------------------------------------------------------
extern "C" void kernel_launch(void* const* d_in, const int* in_sizes, int n_in,
                              void* d_out, int out_size, void* d_ws, size_t ws_size,
                              hipStream_t stream)
{
    const float* x     = (const float*)d_in[0];
    const float* Wq    = (const float*)d_in[1];
    const float* Wkv   = (const float*)d_in[2];
    const float* Wout  = (const float*)d_in[3];
    const float* nkv   = (const float*)d_in[4];
    const float* rot_q = (const float*)d_in[5];
    const float* rot_k = (const float*)d_in[6];
    float* out = (float*)d_out;
    char* wsb  = (char*)d_ws;   // needs ~87 MB

    prep<<<dim3(PREP_BLOCKS), 256, 0, stream>>>(x, Wq, Wkv, Wout, nkv,
                                                rot_q, rot_k, wsb);

    qkv_proj<<<dim3(64, 12, 2), 256, 0, stream>>>(wsb);

    attn<<<dim3(BGH * 16), 256, 0, stream>>>((const unsigned short*)(wsb + QB_B),
                                             (const unsigned short*)(wsb + KB_B),
                                             (const unsigned short*)(wsb + VT_B),
                                             (unsigned short*)(wsb + OB_B));

    out_proj<<<dim3(64, 4, 2), 256, 0, stream>>>(wsb, out);
}